// Round 10
// baseline (36.870 us; speedup 1.0000x reference)
//
#include <hip/hip_runtime.h>
#include <hip/hip_fp16.h>
#include <math.h>

// Problem constants (match reference)
#define BB 64
#define HH 224
#define WW 224
#define CC 3

constexpr float FACTOR  = 0.2f;
constexpr float SCALE_K = 1.0f / 255.0f;
constexpr float TWO_PI_F = 6.283185307179586f;
constexpr float CX = (WW - 1) * 0.5f;            // 111.5
constexpr float CY = (HH - 1) * 0.5f;            // 111.5
constexpr int PIX = HH * WW;                     // 50176
constexpr int IMG_ELEMS = PIX * CC;              // 150528

constexpr int NXCD = 8;

// 32x16 tiles (both kernels)
constexpr int T2X = WW / 32;                     // 7
constexpr int T2Y = HH / 16;                     // 14
constexpr int TILES2 = T2X * T2Y;                // 98
constexpr int NBLOCKS2 = BB * TILES2;            // 6272

constexpr int SZP = 50;   // staged-window row pitch (uint2 units; even)
constexpr int ZP2 = 34;   // Z row pitch (float4 units)

typedef float f32x4 __attribute__((ext_vector_type(4), aligned(4)));
typedef float f32x2 __attribute__((ext_vector_type(2), aligned(4)));
typedef unsigned int u32x4 __attribute__((ext_vector_type(4), aligned(8)));

// Valid for i in [-n, 2n-1] — true for every coordinate in this pipeline.
__device__ __forceinline__ int reflect1(int i, int n) {
    i = (i < 0) ? (-1 - i) : i;
    return (i >= n) ? (2 * n - 1 - i) : i;
}

// Hull [lo,hi] of reflect1 over the integer range [a,b].
__device__ __forceinline__ void rhull(int a, int b, int n, int& lo, int& hi) {
    int ra = reflect1(a, n), rb = reflect1(b, n);
    lo = min(ra, rb); hi = max(ra, rb);
    if (a <= 0 && b >= -1) lo = 0;
    if (b >= n - 1 && a <= n) hi = n - 1;
}

__device__ __forceinline__ float h2f(unsigned short u) {
    return __half2float(__ushort_as_half(u));
}

// shared tile decode: block i -> XCD i%8; batch b pinned to XCD b%8 in BOTH
// kernels (tmp stays in the same per-XCD L2: 8 img x 401KB fp16 = 3.2MB).
__device__ __forceinline__ void decode_tile32(int bid, int& b, int& ox, int& oy) {
    int xcd  = bid & (NXCD - 1);
    int slot = bid >> 3;
    int bi   = slot / TILES2;
    int t    = slot - bi * TILES2;
    b = xcd + bi * NXCD;
    int ty = t / T2X;
    int tx = t - ty * T2X;
    ox = tx * 32; oy = ty * 16;
}

// ============================ K1: rescale + rotate ============================
// R5's proven per-pixel gather body, now 2 px/thread (rows y, y+8) for 2x
// memory-level parallelism: 8 scattered loads in flight per thread, half the
// per-pixel tile/trig/param overhead. Stores stay row-coalesced.
__global__ __launch_bounds__(256)
void rotate_kernel(const float* __restrict__ image, uint2* __restrict__ tmp,
                   const float* __restrict__ angle_u) {
    int b, ox, oy;
    decode_tile32(blockIdx.x, b, ox, oy);
    const int lx = threadIdx.x & 31, ly = threadIdx.x >> 5;  // ly 0..7
    const int x = ox + lx;

    const float theta = (2.0f * angle_u[b] - 1.0f) * FACTOR * TWO_PI_F;
    const float c = __cosf(theta), s = __sinf(theta);
    const float rx = (float)x - CX;
    const float* img = image + (size_t)b * IMG_ELEMS;

    // --- coord + load phase for both pixels (loads batched for ILP) ---
    float fx[2], fy[2];
    bool sA[2], sB[2];
    f32x4 t4[2], b4[2];
    f32x2 t2[2], b2[2];
#pragma unroll
    for (int k = 0; k < 2; ++k) {
        const int y = oy + ly + k * 8;
        const float ry = (float)y - CY;
        const float xs = c * rx - s * ry + CX;
        const float ys = s * rx + c * ry + CY;
        const float x0f = floorf(xs), y0f = floorf(ys);
        fx[k] = xs - x0f; fy[k] = ys - y0f;
        const int x0 = (int)x0f, y0 = (int)y0f;
        const int x0r = reflect1(x0,     WW);
        const int x1r = reflect1(x0 + 1, WW);
        const int y0r = reflect1(y0,     HH);
        const int y1r = reflect1(y0 + 1, HH);
        int xl = min(x0r, x1r); xl = min(xl, WW - 2);
        sA[k] = (x0r != xl);
        sB[k] = (x1r != xl);
        const float* rT = img + (y0r * WW + xl) * CC;
        const float* rB = img + (y1r * WW + xl) * CC;
        t4[k] = *(const f32x4*)rT;
        t2[k] = *(const f32x2*)(rT + 4);
        b4[k] = *(const f32x4*)rB;
        b2[k] = *(const f32x2*)(rB + 4);
    }

    // --- blend + pack + store phase ---
#pragma unroll
    for (int k = 0; k < 2; ++k) {
        const int y = oy + ly + k * 8;
        float TA[3] = { sA[k] ? t4[k].w : t4[k].x, sA[k] ? t2[k].x : t4[k].y, sA[k] ? t2[k].y : t4[k].z };
        float TB[3] = { sB[k] ? t4[k].w : t4[k].x, sB[k] ? t2[k].x : t4[k].y, sB[k] ? t2[k].y : t4[k].z };
        float BA[3] = { sA[k] ? b4[k].w : b4[k].x, sA[k] ? b2[k].x : b4[k].y, sA[k] ? b2[k].y : b4[k].z };
        float BC[3] = { sB[k] ? b4[k].w : b4[k].x, sB[k] ? b2[k].x : b4[k].y, sB[k] ? b2[k].y : b4[k].z };
        const float omfx = 1.0f - fx[k], omfy = 1.0f - fy[k];
        float o[3];
#pragma unroll
        for (int ch = 0; ch < CC; ++ch) {
            float top = TA[ch] * omfx + TB[ch] * fx[k];
            float bot = BA[ch] * omfx + BC[ch] * fx[k];
            o[ch] = (top * omfy + bot * fy[k]) * SCALE_K;
        }
        uint2 v;
        v.x = (unsigned)__half_as_ushort(__float2half_rn(o[0])) |
              ((unsigned)__half_as_ushort(__float2half_rn(o[1])) << 16);
        v.y = (unsigned)__half_as_ushort(__float2half_rn(o[2]));
        tmp[(size_t)b * PIX + (size_t)y * WW + x] = v;
    }
}

// ====================== K2: zoom + translate + flip ==========================
// Verbatim from R9 (best measured): coalesced LDS staging, descriptor-based
// separable zoom, fp32 Z in LDS, uniform translate blend.
__global__ __launch_bounds__(256)
void zoomshift_kernel(const uint2* __restrict__ tmp, float* __restrict__ out,
                      const float* __restrict__ zoom_u,
                      const float* __restrict__ shift_u,
                      const float* __restrict__ flip_u) {
    __shared__ uint2  Sz[24 * SZP];     // 9.4 KB staged tmp window (fp16 px)
    __shared__ float4 Z[17 * ZP2];      // 9.0 KB zoom-stage values
    __shared__ float4 XD[33], YD[17];   // zoom descriptors {frac, tapA, tapB}

    const int tid = threadIdx.x;
    int b, ox, oy;
    decode_tile32(blockIdx.x, b, ox, oy);

    const float zh = 1.0f + (2.0f * zoom_u[2 * b + 0] - 1.0f) * FACTOR;
    const float zw = 1.0f + (2.0f * zoom_u[2 * b + 1] - 1.0f) * FACTOR;
    const float dy = ((2.0f * shift_u[2 * b + 0] - 1.0f) * FACTOR) * (float)HH;
    const float dx = ((2.0f * shift_u[2 * b + 1] - 1.0f) * FACTOR) * (float)WW;
    const bool flip = flip_u[b] > 0.5f;

    const float ndxf = floorf(-dx), ndyf = floorf(-dy);
    const int Kx = (int)ndxf, Ky = (int)ndyf;
    const float fx3 = -dx - ndxf, fy3 = -dy - ndyf;  // batch-uniform weights

    // translate window raw origin (flip folded into output x)
    const int Xmin = (flip ? WW - 32 - ox : ox) + Kx;
    const int Ymin = oy + Ky;

    // staged-window bounds: reflect hull -> zoom tap range (monotone) -> hull
    int XrLo, XrHi, YrLo, YrHi;
    rhull(Xmin, Xmin + 32, WW, XrLo, XrHi);
    rhull(Ymin, Ymin + 16, HH, YrLo, YrHi);
    const int Gx0 = (int)floorf(zw * ((float)XrLo - CX) + CX);
    const int Gx1 = (int)floorf(zw * ((float)XrHi - CX) + CX) + 1;
    const int Gy0 = (int)floorf(zh * ((float)YrLo - CY) + CY);
    const int Gy1 = (int)floorf(zh * ((float)YrHi - CY) + CY) + 1;
    int Cx0, Cx1, Cy0, Cy1;
    rhull(Gx0, Gx1, WW, Cx0, Cx1);     // width <= 41
    rhull(Gy0, Gy1, HH, Cy0, Cy1);     // height <= 22
    const int ColBase = max(min(Cx0, WW - 48), 0) & ~1;   // 48-px window, even
    const int RowBase = max(min(Cy0, HH - 24), 0);        // 24-row window

    // --- phase 0a: coalesced stage (24 rows x 24 x 16B groups = 576 items) ---
    const uint2* timg = tmp + (size_t)b * PIX;
    for (int id = tid; id < 576; id += 256) {
        const int row = id / 24;
        const int g   = id - row * 24;
        u32x4 v = *(const u32x4*)(timg + (size_t)(RowBase + row) * WW + ColBase + g * 2);
        *(u32x4*)(&Sz[row * SZP + g * 2]) = v;
    }

    // --- phase 0b: zoom descriptors (exact reference expressions) ---
    if (tid < 33) {
        const int Xr = reflect1(Xmin + tid, WW);
        const float xs2 = zw * ((float)Xr - CX) + CX;
        const float xf = floorf(xs2);
        const int x20 = (int)xf;
        const int cA = min(max(reflect1(x20,     WW) - ColBase, 0), 47);
        const int cB = min(max(reflect1(x20 + 1, WW) - ColBase, 0), 47);
        XD[tid] = make_float4(xs2 - xf, __int_as_float(cA), __int_as_float(cB), 0.f);
    } else if (tid >= 64 && tid < 81) {
        const int ey = tid - 64;
        const int Yr = reflect1(Ymin + ey, HH);
        const float ys2 = zh * ((float)Yr - CY) + CY;
        const float yf = floorf(ys2);
        const int y20 = (int)yf;
        const int rA = min(max(reflect1(y20,     HH) - RowBase, 0), 23) * SZP;
        const int rB = min(max(reflect1(y20 + 1, HH) - RowBase, 0), 23) * SZP;
        YD[ey] = make_float4(ys2 - yf, __int_as_float(rA), __int_as_float(rB), 0.f);
    }
    __syncthreads();

    // --- phase 1: Z[17][33] zoom-stage values, taps from LDS ---
    for (int e = tid; e < 17 * 33; e += 256) {
        const int ey = e / 33;
        const int ex = e - ey * 33;
        const float4 xd = XD[ex];
        const float4 yd = YD[ey];
        const int cA = __float_as_int(xd.y), cB = __float_as_int(xd.z);
        const int rA = __float_as_int(yd.y), rB = __float_as_int(yd.z);
        const uint2 va = Sz[rA + cA];
        const uint2 vb = Sz[rA + cB];
        const uint2 vc = Sz[rB + cA];
        const uint2 vd = Sz[rB + cB];
        const float fx2 = xd.x, fy2 = yd.x;
        const float ofx = 1.0f - fx2, ofy = 1.0f - fy2;
        float4 res;
        res.x = (h2f((unsigned short)(va.x & 0xffffu)) * ofx + h2f((unsigned short)(vb.x & 0xffffu)) * fx2) * ofy
              + (h2f((unsigned short)(vc.x & 0xffffu)) * ofx + h2f((unsigned short)(vd.x & 0xffffu)) * fx2) * fy2;
        res.y = (h2f((unsigned short)(va.x >> 16)) * ofx + h2f((unsigned short)(vb.x >> 16)) * fx2) * ofy
              + (h2f((unsigned short)(vc.x >> 16)) * ofx + h2f((unsigned short)(vd.x >> 16)) * fx2) * fy2;
        res.z = (h2f((unsigned short)(va.y & 0xffffu)) * ofx + h2f((unsigned short)(vb.y & 0xffffu)) * fx2) * ofy
              + (h2f((unsigned short)(vc.y & 0xffffu)) * ofx + h2f((unsigned short)(vd.y & 0xffffu)) * fx2) * fy2;
        res.w = 0.f;
        Z[ey * ZP2 + ex] = res;
    }
    __syncthreads();

    // --- phase 2: translate blend + flip, 2 px/thread, write output ---
    const float ofx = 1.0f - fx3, ofy = 1.0f - fy3;
#pragma unroll
    for (int i = 0; i < 2; ++i) {
        const int p  = tid + 256 * i;
        const int lx = p & 31, ly = p >> 5;
        const int ix = flip ? (31 - lx) : lx;
        const float4 A  = Z[ly * ZP2 + ix];
        const float4 Bv = Z[ly * ZP2 + ix + 1];
        const float4 Cv = Z[(ly + 1) * ZP2 + ix];
        const float4 Dv = Z[(ly + 1) * ZP2 + ix + 1];
        float* o = out + ((size_t)b * PIX + (size_t)(oy + ly) * WW + (ox + lx)) * CC;
        o[0] = (A.x * ofx + Bv.x * fx3) * ofy + (Cv.x * ofx + Dv.x * fx3) * fy3;
        o[1] = (A.y * ofx + Bv.y * fx3) * ofy + (Cv.y * ofx + Dv.y * fx3) * fy3;
        o[2] = (A.z * ofx + Bv.z * fx3) * ofy + (Cv.z * ofx + Dv.z * fx3) * fy3;
    }
}

extern "C" void kernel_launch(void* const* d_in, const int* in_sizes, int n_in,
                              void* d_out, int out_size, void* d_ws, size_t ws_size,
                              hipStream_t stream) {
    const float* image   = (const float*)d_in[0];
    const float* angle_u = (const float*)d_in[1];
    const float* zoom_u  = (const float*)d_in[2];
    const float* shift_u = (const float*)d_in[3];
    const float* flip_u  = (const float*)d_in[4];
    float* out = (float*)d_out;

    uint2* tmp = (uint2*)d_ws;   // B*H*W packed fp16 RGBA, 25.7 MB

    // pass 1: rescale + rotate   image -> tmp (fp16), 2 px/thread
    rotate_kernel<<<NBLOCKS2, 256, 0, stream>>>(image, tmp, angle_u);
    // pass 2+3 fused: zoom + translate + flip   tmp -> d_out
    zoomshift_kernel<<<NBLOCKS2, 256, 0, stream>>>(tmp, out, zoom_u, shift_u, flip_u);
}

// Round 11
// 35.737 us; speedup vs baseline: 1.0317x; 1.0317x over previous
//
#include <hip/hip_runtime.h>
#include <hip/hip_fp16.h>
#include <math.h>

// Problem constants (match reference)
#define BB 64
#define HH 224
#define WW 224
#define CC 3

constexpr float FACTOR  = 0.2f;
constexpr float SCALE_K = 1.0f / 255.0f;
constexpr float TWO_PI_F = 6.283185307179586f;
constexpr float CX = (WW - 1) * 0.5f;            // 111.5
constexpr float CY = (HH - 1) * 0.5f;            // 111.5
constexpr int PIX = HH * WW;                     // 50176
constexpr int IMG_ELEMS = PIX * CC;              // 150528

constexpr int NXCD = 8;

// 32x16 tiles (both kernels)
constexpr int T2X = WW / 32;                     // 7
constexpr int T2Y = HH / 16;                     // 14
constexpr int TILES2 = T2X * T2Y;                // 98
constexpr int NBLOCKS2 = BB * TILES2;            // 6272

constexpr int SZP = 50;   // K2 staged-window row pitch (uint2 units; even)
constexpr int ZP2 = 34;   // K2 Z row pitch (float4 units)

// K1 staged window: rotated-bbox tap hull of a 32x16 tile is <=37x37
// (sqrt(31^2+15^2)+2 = 36.5); window 40x38, 4-px-aligned columns.
constexpr int WINW = 40;
constexpr int WINH = 38;

typedef float f32x4 __attribute__((ext_vector_type(4), aligned(4)));
typedef unsigned int u32x4 __attribute__((ext_vector_type(4), aligned(8)));

// Valid for i in [-n, 2n-1] — true for every coordinate in this pipeline.
__device__ __forceinline__ int reflect1(int i, int n) {
    i = (i < 0) ? (-1 - i) : i;
    return (i >= n) ? (2 * n - 1 - i) : i;
}

// Hull [lo,hi] of reflect1 over the integer range [a,b].
__device__ __forceinline__ void rhull(int a, int b, int n, int& lo, int& hi) {
    int ra = reflect1(a, n), rb = reflect1(b, n);
    lo = min(ra, rb); hi = max(ra, rb);
    if (a <= 0 && b >= -1) lo = 0;
    if (b >= n - 1 && a <= n) hi = n - 1;
}

__device__ __forceinline__ float h2f(unsigned short u) {
    return __half2float(__ushort_as_half(u));
}

__device__ __forceinline__ uint2 pack3(float a, float b, float c) {
    uint2 v;
    v.x = (unsigned)__half_as_ushort(__float2half_rn(a)) |
          ((unsigned)__half_as_ushort(__float2half_rn(b)) << 16);
    v.y = (unsigned)__half_as_ushort(__float2half_rn(c));
    return v;
}

// block i -> XCD i%8; batch b pinned to XCD b%8 in BOTH kernels
// (tmp stays in the same per-XCD L2: 8 img x 401KB fp16 = 3.2MB).
__device__ __forceinline__ void decode_tile32(int bid, int& b, int& ox, int& oy) {
    int xcd  = bid & (NXCD - 1);
    int slot = bid >> 3;
    int bi   = slot / TILES2;
    int t    = slot - bi * TILES2;
    b = xcd + bi * NXCD;
    int ty = t / T2X;
    int tx = t - ty * T2X;
    ox = tx * 32; oy = ty * 16;
}

// ============================ K1: rescale + rotate ============================
// Scattered global gathers replaced by: coalesced stage of the provably
// sufficient 40x38 window (pre-scaled, fp16-RGBA packed) -> 4 aligned 8B LDS
// taps per output pixel. Cuts per-block L1 transactions ~15x at the cost of
// modest extra VALU (fp16 cvt) — attacking the measured TA-transaction bound.
__global__ __launch_bounds__(256)
void rotate_kernel(const float* __restrict__ image, uint2* __restrict__ tmp,
                   const float* __restrict__ angle_u) {
    __shared__ uint2 SW[WINH * WINW];   // 12.2 KB

    const int tid = threadIdx.x;
    int b, ox, oy;
    decode_tile32(blockIdx.x, b, ox, oy);

    const float theta = (2.0f * angle_u[b] - 1.0f) * FACTOR * TWO_PI_F;
    const float c = __cosf(theta), s = __sinf(theta);

    // rotated bbox of the 32x16 tile -> tap hull -> clamped window origin
    const float rx0 = (float)ox - CX, rx1 = (float)(ox + 31) - CX;
    const float ry0 = (float)oy - CY, ry1 = (float)(oy + 15) - CY;
    const float xsmin = fminf(c * rx0, c * rx1) + fminf(-s * ry0, -s * ry1) + CX;
    const float xsmax = fmaxf(c * rx0, c * rx1) + fmaxf(-s * ry0, -s * ry1) + CX;
    const float ysmin = fminf(s * rx0, s * rx1) + fminf(c * ry0, c * ry1) + CY;
    const float ysmax = fmaxf(s * rx0, s * rx1) + fmaxf(c * ry0, c * ry1) + CY;
    int Cx0, Cx1, Cy0, Cy1;
    rhull((int)floorf(xsmin), (int)floorf(xsmax) + 1, WW, Cx0, Cx1);
    rhull((int)floorf(ysmin), (int)floorf(ysmax) + 1, HH, Cy0, Cy1);
    // 4-aligned so 4-px groups are 48B/16B-aligned; window always covers hull:
    // ColBase >= Cx0-3 and Cx1-Cx0 <= 36 -> Cx1 <= ColBase+39.
    const int ColBase = min(Cx0 & ~3, WW - WINW);
    const int RowBase = min(Cy0, HH - WINH);

    // --- stage: 38 rows x 10 groups of 4 px; 3 x f32x4 -> 2 x 16B LDS ---
    const float* img = image + (size_t)b * IMG_ELEMS;
    for (int id = tid; id < WINH * (WINW / 4); id += 256) {       // 380 items
        const int r = id / (WINW / 4);
        const int g = id - r * (WINW / 4);
        const float* src = img + ((size_t)(RowBase + r) * WW + ColBase + g * 4) * CC;
        f32x4 v0 = *(const f32x4*)(src);
        f32x4 v1 = *(const f32x4*)(src + 4);
        f32x4 v2 = *(const f32x4*)(src + 8);
        uint2 p0 = pack3(v0.x * SCALE_K, v0.y * SCALE_K, v0.z * SCALE_K);
        uint2 p1 = pack3(v0.w * SCALE_K, v1.x * SCALE_K, v1.y * SCALE_K);
        uint2 p2 = pack3(v1.z * SCALE_K, v1.w * SCALE_K, v2.x * SCALE_K);
        uint2 p3 = pack3(v2.y * SCALE_K, v2.z * SCALE_K, v2.w * SCALE_K);
        u32x4 q0 = { p0.x, p0.y, p1.x, p1.y };
        u32x4 q1 = { p2.x, p2.y, p3.x, p3.y };
        *(u32x4*)(&SW[r * WINW + g * 4])     = q0;
        *(u32x4*)(&SW[r * WINW + g * 4 + 2]) = q1;
    }
    __syncthreads();

    // --- taps + blend: 2 px/thread (rows y, y+8) ---
    const int lx = tid & 31, lyy = tid >> 5;
    const int x = ox + lx;
    const float rxv = (float)x - CX;
#pragma unroll
    for (int k = 0; k < 2; ++k) {
        const int y = oy + lyy + k * 8;
        const float ryv = (float)y - CY;
        const float xs = c * rxv - s * ryv + CX;
        const float ys = s * rxv + c * ryv + CY;
        const float xf = floorf(xs), yf = floorf(ys);
        const float fx = xs - xf, fy = ys - yf;
        const int x0 = (int)xf, y0 = (int)yf;
        const int c0 = min(max(reflect1(x0,     WW) - ColBase, 0), WINW - 1);
        const int c1 = min(max(reflect1(x0 + 1, WW) - ColBase, 0), WINW - 1);
        const int r0 = min(max(reflect1(y0,     HH) - RowBase, 0), WINH - 1);
        const int r1 = min(max(reflect1(y0 + 1, HH) - RowBase, 0), WINH - 1);
        const uint2 va = SW[r0 * WINW + c0];
        const uint2 vb = SW[r0 * WINW + c1];
        const uint2 vc = SW[r1 * WINW + c0];
        const uint2 vd = SW[r1 * WINW + c1];
        const float ofx = 1.0f - fx, ofy = 1.0f - fy;
        const float o0 =
            (h2f((unsigned short)(va.x & 0xffffu)) * ofx + h2f((unsigned short)(vb.x & 0xffffu)) * fx) * ofy +
            (h2f((unsigned short)(vc.x & 0xffffu)) * ofx + h2f((unsigned short)(vd.x & 0xffffu)) * fx) * fy;
        const float o1 =
            (h2f((unsigned short)(va.x >> 16)) * ofx + h2f((unsigned short)(vb.x >> 16)) * fx) * ofy +
            (h2f((unsigned short)(vc.x >> 16)) * ofx + h2f((unsigned short)(vd.x >> 16)) * fx) * fy;
        const float o2 =
            (h2f((unsigned short)(va.y & 0xffffu)) * ofx + h2f((unsigned short)(vb.y & 0xffffu)) * fx) * ofy +
            (h2f((unsigned short)(vc.y & 0xffffu)) * ofx + h2f((unsigned short)(vd.y & 0xffffu)) * fx) * fy;
        tmp[(size_t)b * PIX + (size_t)y * WW + x] = pack3(o0, o1, o2);
    }
}

// ====================== K2: zoom + translate + flip ==========================
// Verbatim from R9 (best measured): coalesced LDS staging, descriptor-based
// separable zoom, fp32 Z in LDS, uniform translate blend.
__global__ __launch_bounds__(256)
void zoomshift_kernel(const uint2* __restrict__ tmp, float* __restrict__ out,
                      const float* __restrict__ zoom_u,
                      const float* __restrict__ shift_u,
                      const float* __restrict__ flip_u) {
    __shared__ uint2  Sz[24 * SZP];     // 9.4 KB staged tmp window (fp16 px)
    __shared__ float4 Z[17 * ZP2];      // 9.0 KB zoom-stage values
    __shared__ float4 XD[33], YD[17];   // zoom descriptors {frac, tapA, tapB}

    const int tid = threadIdx.x;
    int b, ox, oy;
    decode_tile32(blockIdx.x, b, ox, oy);

    const float zh = 1.0f + (2.0f * zoom_u[2 * b + 0] - 1.0f) * FACTOR;
    const float zw = 1.0f + (2.0f * zoom_u[2 * b + 1] - 1.0f) * FACTOR;
    const float dy = ((2.0f * shift_u[2 * b + 0] - 1.0f) * FACTOR) * (float)HH;
    const float dx = ((2.0f * shift_u[2 * b + 1] - 1.0f) * FACTOR) * (float)WW;
    const bool flip = flip_u[b] > 0.5f;

    const float ndxf = floorf(-dx), ndyf = floorf(-dy);
    const int Kx = (int)ndxf, Ky = (int)ndyf;
    const float fx3 = -dx - ndxf, fy3 = -dy - ndyf;  // batch-uniform weights

    // translate window raw origin (flip folded into output x)
    const int Xmin = (flip ? WW - 32 - ox : ox) + Kx;
    const int Ymin = oy + Ky;

    // staged-window bounds: reflect hull -> zoom tap range (monotone) -> hull
    int XrLo, XrHi, YrLo, YrHi;
    rhull(Xmin, Xmin + 32, WW, XrLo, XrHi);
    rhull(Ymin, Ymin + 16, HH, YrLo, YrHi);
    const int Gx0 = (int)floorf(zw * ((float)XrLo - CX) + CX);
    const int Gx1 = (int)floorf(zw * ((float)XrHi - CX) + CX) + 1;
    const int Gy0 = (int)floorf(zh * ((float)YrLo - CY) + CY);
    const int Gy1 = (int)floorf(zh * ((float)YrHi - CY) + CY) + 1;
    int Cx0, Cx1, Cy0, Cy1;
    rhull(Gx0, Gx1, WW, Cx0, Cx1);     // width <= 41
    rhull(Gy0, Gy1, HH, Cy0, Cy1);     // height <= 22
    const int ColBase = max(min(Cx0, WW - 48), 0) & ~1;   // 48-px window, even
    const int RowBase = max(min(Cy0, HH - 24), 0);        // 24-row window

    // --- phase 0a: coalesced stage (24 rows x 24 x 16B groups = 576 items) ---
    const uint2* timg = tmp + (size_t)b * PIX;
    for (int id = tid; id < 576; id += 256) {
        const int row = id / 24;
        const int g   = id - row * 24;
        u32x4 v = *(const u32x4*)(timg + (size_t)(RowBase + row) * WW + ColBase + g * 2);
        *(u32x4*)(&Sz[row * SZP + g * 2]) = v;
    }

    // --- phase 0b: zoom descriptors (exact reference expressions) ---
    if (tid < 33) {
        const int Xr = reflect1(Xmin + tid, WW);
        const float xs2 = zw * ((float)Xr - CX) + CX;
        const float xf = floorf(xs2);
        const int x20 = (int)xf;
        const int cA = min(max(reflect1(x20,     WW) - ColBase, 0), 47);
        const int cB = min(max(reflect1(x20 + 1, WW) - ColBase, 0), 47);
        XD[tid] = make_float4(xs2 - xf, __int_as_float(cA), __int_as_float(cB), 0.f);
    } else if (tid >= 64 && tid < 81) {
        const int ey = tid - 64;
        const int Yr = reflect1(Ymin + ey, HH);
        const float ys2 = zh * ((float)Yr - CY) + CY;
        const float yf = floorf(ys2);
        const int y20 = (int)yf;
        const int rA = min(max(reflect1(y20,     HH) - RowBase, 0), 23) * SZP;
        const int rB = min(max(reflect1(y20 + 1, HH) - RowBase, 0), 23) * SZP;
        YD[ey] = make_float4(ys2 - yf, __int_as_float(rA), __int_as_float(rB), 0.f);
    }
    __syncthreads();

    // --- phase 1: Z[17][33] zoom-stage values, taps from LDS ---
    for (int e = tid; e < 17 * 33; e += 256) {
        const int ey = e / 33;
        const int ex = e - ey * 33;
        const float4 xd = XD[ex];
        const float4 yd = YD[ey];
        const int cA = __float_as_int(xd.y), cB = __float_as_int(xd.z);
        const int rA = __float_as_int(yd.y), rB = __float_as_int(yd.z);
        const uint2 va = Sz[rA + cA];
        const uint2 vb = Sz[rA + cB];
        const uint2 vc = Sz[rB + cA];
        const uint2 vd = Sz[rB + cB];
        const float fx2 = xd.x, fy2 = yd.x;
        const float ofx = 1.0f - fx2, ofy = 1.0f - fy2;
        float4 res;
        res.x = (h2f((unsigned short)(va.x & 0xffffu)) * ofx + h2f((unsigned short)(vb.x & 0xffffu)) * fx2) * ofy
              + (h2f((unsigned short)(vc.x & 0xffffu)) * ofx + h2f((unsigned short)(vd.x & 0xffffu)) * fx2) * fy2;
        res.y = (h2f((unsigned short)(va.x >> 16)) * ofx + h2f((unsigned short)(vb.x >> 16)) * fx2) * ofy
              + (h2f((unsigned short)(vc.x >> 16)) * ofx + h2f((unsigned short)(vd.x >> 16)) * fx2) * fy2;
        res.z = (h2f((unsigned short)(va.y & 0xffffu)) * ofx + h2f((unsigned short)(vb.y & 0xffffu)) * fx2) * ofy
              + (h2f((unsigned short)(vc.y & 0xffffu)) * ofx + h2f((unsigned short)(vd.y & 0xffffu)) * fx2) * fy2;
        res.w = 0.f;
        Z[ey * ZP2 + ex] = res;
    }
    __syncthreads();

    // --- phase 2: translate blend + flip, 2 px/thread, write output ---
    const float ofx = 1.0f - fx3, ofy = 1.0f - fy3;
#pragma unroll
    for (int i = 0; i < 2; ++i) {
        const int p  = tid + 256 * i;
        const int lx = p & 31, ly = p >> 5;
        const int ix = flip ? (31 - lx) : lx;
        const float4 A  = Z[ly * ZP2 + ix];
        const float4 Bv = Z[ly * ZP2 + ix + 1];
        const float4 Cv = Z[(ly + 1) * ZP2 + ix];
        const float4 Dv = Z[(ly + 1) * ZP2 + ix + 1];
        float* o = out + ((size_t)b * PIX + (size_t)(oy + ly) * WW + (ox + lx)) * CC;
        o[0] = (A.x * ofx + Bv.x * fx3) * ofy + (Cv.x * ofx + Dv.x * fx3) * fy3;
        o[1] = (A.y * ofx + Bv.y * fx3) * ofy + (Cv.y * ofx + Dv.y * fx3) * fy3;
        o[2] = (A.z * ofx + Bv.z * fx3) * ofy + (Cv.z * ofx + Dv.z * fx3) * fy3;
    }
}

extern "C" void kernel_launch(void* const* d_in, const int* in_sizes, int n_in,
                              void* d_out, int out_size, void* d_ws, size_t ws_size,
                              hipStream_t stream) {
    const float* image   = (const float*)d_in[0];
    const float* angle_u = (const float*)d_in[1];
    const float* zoom_u  = (const float*)d_in[2];
    const float* shift_u = (const float*)d_in[3];
    const float* flip_u  = (const float*)d_in[4];
    float* out = (float*)d_out;

    uint2* tmp = (uint2*)d_ws;   // B*H*W packed fp16 RGBA, 25.7 MB

    // pass 1: rescale + rotate   image -> tmp (fp16), LDS-windowed taps
    rotate_kernel<<<NBLOCKS2, 256, 0, stream>>>(image, tmp, angle_u);
    // pass 2+3 fused: zoom + translate + flip   tmp -> d_out
    zoomshift_kernel<<<NBLOCKS2, 256, 0, stream>>>(tmp, out, zoom_u, shift_u, flip_u);
}